// Round 3
// baseline (413.408 us; speedup 1.0000x reference)
//
#include <hip/hip_runtime.h>
#include <hip/hip_bf16.h>
#include <cstdint>

// Problem constants
#define Bb 4
#define Ss 4096
#define Dd 1024
#define Hh 8
#define DI 2048
#define HD 256
#define XZN 4096      // 2*DI
#define Mtot 16384    // B*S
#define NCH 128       // scan chunks
#define CHUNK 32      // S / NCH

typedef __bf16 bf16_t;
typedef __bf16 bf16x8 __attribute__((ext_vector_type(8)));
typedef __bf16 bf16x4 __attribute__((ext_vector_type(4)));
typedef float f32x4 __attribute__((ext_vector_type(4)));

__device__ __forceinline__ float sigmoidf_(float x) { return 1.f / (1.f + __expf(-x)); }

// async 16B/lane global->LDS. LDS dest is wave-uniform base + lane*16.
__device__ __forceinline__ void async_ld16(void* lds, const void* g) {
  __builtin_amdgcn_global_load_lds(
      (const __attribute__((address_space(1))) void*)(uintptr_t)g,
      (__attribute__((address_space(3))) void*)(uint32_t)(uintptr_t)lds,
      16, 0, 0);
}

// ---------------- fp32 -> bf16 cast (weights) ----------------
__global__ __launch_bounds__(256) void cvt_kernel(const float* __restrict__ s,
                                                  bf16_t* __restrict__ d) {
  const int i = blockIdx.x * 256 + threadIdx.x;  // one float4 per thread
  const float4 v = ((const float4*)s)[i];
  bf16_t* o = d + 4 * (size_t)i;
  o[0] = (bf16_t)v.x; o[1] = (bf16_t)v.y; o[2] = (bf16_t)v.z; o[3] = (bf16_t)v.w;
}

// ---------------- LayerNorm -> bf16 ----------------
__global__ __launch_bounds__(256) void ln_kernel(const float* __restrict__ x,
                                                 const float* __restrict__ w,
                                                 const float* __restrict__ b,
                                                 bf16_t* __restrict__ xn) {
  __shared__ float red[8];
  const int row = blockIdx.x;
  const float4 v = ((const float4*)(x + (size_t)row * Dd))[threadIdx.x];
  float s  = v.x + v.y + v.z + v.w;
  float s2 = v.x * v.x + v.y * v.y + v.z * v.z + v.w * v.w;
  #pragma unroll
  for (int off = 32; off; off >>= 1) { s += __shfl_down(s, off); s2 += __shfl_down(s2, off); }
  const int wave = threadIdx.x >> 6, lane = threadIdx.x & 63;
  if (lane == 0) { red[wave * 2] = s; red[wave * 2 + 1] = s2; }
  __syncthreads();
  if (threadIdx.x == 0) {
    float S = 0.f, S2 = 0.f;
    for (int i = 0; i < 4; ++i) { S += red[i * 2]; S2 += red[i * 2 + 1]; }
    red[0] = S; red[1] = S2;
  }
  __syncthreads();
  const float mean = red[0] * (1.f / Dd);
  const float var  = red[1] * (1.f / Dd) - mean * mean;
  const float rstd = rsqrtf(var + 1e-5f);
  const float4 wv = ((const float4*)w)[threadIdx.x];
  const float4 bv = ((const float4*)b)[threadIdx.x];
  bf16_t* o = xn + (size_t)row * Dd + threadIdx.x * 4;
  o[0] = (bf16_t)((v.x - mean) * rstd * wv.x + bv.x);
  o[1] = (bf16_t)((v.y - mean) * rstd * wv.y + bv.y);
  o[2] = (bf16_t)((v.z - mean) * rstd * wv.z + bv.z);
  o[3] = (bf16_t)((v.w - mean) * rstd * wv.w + bv.w);
}

// ---------------- GEMM: C[M,N] = A[M,K] @ B[N,K]^T (both K-major bf16) ----------------
// 256x256 tile, BK=32, 8 waves (2M x 4N, each 128x64 out), 16x16x32 bf16 MFMA.
// 4-deep LDS ring (4 x 32KB = 128 KiB), counted-vmcnt pipeline (T3/T4) with
// REGISTER-LEVEL fragment pipelining: per K-tile t we
//   vmcnt(4) [tile t+1 landed; t+2 in flight] + one s_barrier,
//   issue 12 ds_read_b128 for tile t+1's fragments (alternate reg set),
//   issue 4 global_load_lds for tile t+3,
//   run 32 MFMA on tile t's fragments (already in registers -> no LDS dep),
// so the LDS drain of t+1 overlaps the MFMA burst of t instead of serializing.
// Race-freedom: a wave passing barrier t has lgkm-drained its tile-(t-1) reads
// (consumed by MFMA before the barrier); staging at barrier t writes buffer
// (t+3)&3 == (t-1)&3. vmcnt peels 4->0 for the last two tiles.
// LDS swizzle (T2): 64B rows of 4x16B chunks, phys_chunk = logical ^ ((row>>1)&3);
// writer pre-swizzles the GLOBAL source address (linear global_load_lds dest).
// Measured conflict-free (SQ_LDS_BANK_CONFLICT == 0).
template <int ADD_RES>
__global__ __launch_bounds__(512, 2) void gemm256(const bf16_t* __restrict__ A,
                                                  const bf16_t* __restrict__ Bw,
                                                  void* __restrict__ Cv,
                                                  const float* __restrict__ res,
                                                  int M, int N, int K) {
  __shared__ __align__(16) bf16_t As[4][8192];   // 4 x 256x32
  __shared__ __align__(16) bf16_t Bs[4][8192];
  const int tid = threadIdx.x;
  const int wave = tid >> 6, lane = tid & 63;
  const int wm = wave >> 2, wn = wave & 3;

  // T1: XCD-aware bijective block swizzle (both grids have nwg % 8 == 0)
  const int nbx = gridDim.x;
  const int nwg = nbx * gridDim.y;
  const int bid0 = blockIdx.y * nbx + blockIdx.x;
  const int cpx = nwg >> 3;
  const int bid = (bid0 & 7) * cpx + (bid0 >> 3);
  const int bm = bid / nbx, bn = bid % nbx;

  f32x4 acc[8][4];
  #pragma unroll
  for (int i = 0; i < 8; ++i)
    #pragma unroll
    for (int j = 0; j < 4; ++j) acc[i][j] = (f32x4){0.f, 0.f, 0.f, 0.f};

  // staging: thread tid covers LDS bytes tid*16 (rows 0..127) and 8192+tid*16
  // (rows 128..255) of each 16KB half. row = l*128 + (tid>>2), phys chunk = tid&3,
  // so the global source chunk is (tid&3) ^ ((row>>1)&3) = (tid&3) ^ ((tid>>3)&3).
  const int srow = tid >> 2;
  const int sc   = (tid & 3) ^ ((tid >> 3) & 3);
  const bf16_t* Ag = A  + (size_t)(bm * 256 + srow) * K + sc * 8;
  const bf16_t* Bg = Bw + (size_t)(bn * 256 + srow) * K + sc * 8;
  const size_t rowK128 = (size_t)128 * K;
  char* const AsB = (char*)As + (wave << 10);   // wave-uniform LDS stage base
  char* const BsB = (char*)Bs + (wave << 10);

  // fragment LDS byte offsets (constant across tiles)
  const int fr = lane & 15, fq = lane >> 4;
  int aoff[8], boff[4];
  #pragma unroll
  for (int mt = 0; mt < 8; ++mt) {
    const int row = wm * 128 + mt * 16 + fr;
    aoff[mt] = row * 64 + ((fq ^ ((row >> 1) & 3)) << 4);
  }
  #pragma unroll
  for (int nt = 0; nt < 4; ++nt) {
    const int row = wn * 64 + nt * 16 + fr;
    boff[nt] = row * 64 + ((fq ^ ((row >> 1) & 3)) << 4);
  }

  const int NT = K >> 5;

#define STAGE(u) do {                                          \
    const int b_ = (u) & 3; const int kt_ = (u) << 5;          \
    async_ld16(AsB + b_ * 16384,        Ag + kt_);             \
    async_ld16(AsB + b_ * 16384 + 8192, Ag + rowK128 + kt_);   \
    async_ld16(BsB + b_ * 16384,        Bg + kt_);             \
    async_ld16(BsB + b_ * 16384 + 8192, Bg + rowK128 + kt_);   \
  } while (0)

#define READF(AF, BF, bufi) do {                                         \
    const char* Ab_ = (const char*)As + (bufi) * 16384;                  \
    const char* Bb_ = (const char*)Bs + (bufi) * 16384;                  \
    _Pragma("unroll")                                                    \
    for (int mt_ = 0; mt_ < 8; ++mt_) AF[mt_] = *(const bf16x8*)(Ab_ + aoff[mt_]); \
    _Pragma("unroll")                                                    \
    for (int nt_ = 0; nt_ < 4; ++nt_) BF[nt_] = *(const bf16x8*)(Bb_ + boff[nt_]); \
  } while (0)

#define MFMA_ALL(AF, BF) do {                                            \
    __builtin_amdgcn_s_setprio(1);                                       \
    _Pragma("unroll")                                                    \
    for (int mt_ = 0; mt_ < 8; ++mt_)                                    \
      _Pragma("unroll")                                                  \
      for (int nt_ = 0; nt_ < 4; ++nt_)                                  \
        acc[mt_][nt_] = __builtin_amdgcn_mfma_f32_16x16x32_bf16(         \
            AF[mt_], BF[nt_], acc[mt_][nt_], 0, 0, 0);                   \
    __builtin_amdgcn_s_setprio(0);                                       \
  } while (0)

#define WAITBAR(u) do {                                                  \
    if ((u) + 2 < NT) asm volatile("s_waitcnt vmcnt(4)" ::: "memory");   \
    else              asm volatile("s_waitcnt vmcnt(0)" ::: "memory");   \
    __builtin_amdgcn_s_barrier();                                        \
  } while (0)

  // prologue: stage tiles 0,1,2 (12 loads in flight), preload tile-0 fragments
  STAGE(0); STAGE(1); STAGE(2);
  asm volatile("s_waitcnt vmcnt(8)" ::: "memory");
  __builtin_amdgcn_s_barrier();
  bf16x8 af0[8], bf0[4], af1[8], bf1[4];
  READF(af0, bf0, 0);

  for (int t = 0; t < NT; t += 2) {
    // ---- tile t: consume set0, prefetch set1 (tile t+1), stage t+3 ----
    WAITBAR(t);
    if (t + 1 < NT) READF(af1, bf1, (t + 1) & 3);
    if (t + 3 < NT) STAGE(t + 3);
    MFMA_ALL(af0, bf0);
    // ---- tile t+1: consume set1, prefetch set0 (tile t+2), stage t+4 ----
    WAITBAR(t + 1);
    if (t + 2 < NT) READF(af0, bf0, (t + 2) & 3);
    if (t + 4 < NT) STAGE(t + 4);
    MFMA_ALL(af1, bf1);
  }

#undef STAGE
#undef READF
#undef MFMA_ALL
#undef WAITBAR

  // epilogue: D[row=fq*4+r][col=fr] per 16x16 tile
  const int m0 = bm * 256 + wm * 128 + fq * 4;
  const int n0 = bn * 256 + wn * 64 + fr;
  #pragma unroll
  for (int mt = 0; mt < 8; ++mt)
    #pragma unroll
    for (int nt = 0; nt < 4; ++nt)
      #pragma unroll
      for (int r = 0; r < 4; ++r) {
        const size_t m = (size_t)(m0 + mt * 16 + r);
        const size_t n = (size_t)(n0 + nt * 16);
        if (ADD_RES)
          ((float*)Cv)[m * N + n] = acc[mt][nt][r] + res[m * N + n];
        else
          ((bf16_t*)Cv)[m * N + n] = (bf16_t)acc[mt][nt][r];
      }
}

// ---------------- scan pass A: conv + chunk-local scan, carries only ----------------
__global__ __launch_bounds__(256) void scanA_kernel(const bf16_t* __restrict__ xz,
                                                    const float* __restrict__ conv_w,
                                                    const float* __restrict__ conv_b,
                                                    const float* __restrict__ log_alpha,
                                                    float* __restrict__ carry) {
  const int half  = blockIdx.x & 1;
  const int chunk = (blockIdx.x >> 1) & (NCH - 1);
  const int b     = blockIdx.x >> 8;
  const int ch    = half * 1024 + threadIdx.x * 4;
  const float alpha = sigmoidf_(log_alpha[ch >> 8]);
  float w[4][4], bias[4];
  #pragma unroll
  for (int j = 0; j < 4; ++j) {
    const float4 cw = ((const float4*)conv_w)[ch + j];
    w[j][0] = cw.x; w[j][1] = cw.y; w[j][2] = cw.z; w[j][3] = cw.w;
    bias[j] = conv_b[ch + j];
  }
  const int s0 = chunk * CHUNK;
  const size_t base = ((size_t)b * Ss + s0) * XZN + ch;
  float x3[4] = {0,0,0,0}, x2[4] = {0,0,0,0}, x1[4] = {0,0,0,0}, y[4] = {0,0,0,0};
  if (chunk > 0) {
    const bf16x4 v3 = *(const bf16x4*)(xz + base - 3 * (size_t)XZN);
    const bf16x4 v2 = *(const bf16x4*)(xz + base - 2 * (size_t)XZN);
    const bf16x4 v1 = *(const bf16x4*)(xz + base - 1 * (size_t)XZN);
    #pragma unroll
    for (int j = 0; j < 4; ++j) { x3[j] = (float)v3[j]; x2[j] = (float)v2[j]; x1[j] = (float)v1[j]; }
  }
  #pragma unroll 4
  for (int t = 0; t < CHUNK; ++t) {
    const bf16x4 v = *(const bf16x4*)(xz + base + (size_t)t * XZN);
    #pragma unroll
    for (int j = 0; j < 4; ++j) {
      const float xc = (float)v[j];
      const float cv = bias[j] + w[j][0] * x3[j] + w[j][1] * x2[j] + w[j][2] * x1[j] + w[j][3] * xc;
      x3[j] = x2[j]; x2[j] = x1[j]; x1[j] = xc;
      y[j] = fmaf(alpha, y[j], cv);
    }
  }
  *(float4*)(carry + ((size_t)b * NCH + chunk) * DI + ch) =
      make_float4(y[0], y[1], y[2], y[3]);
}

// ---------------- scan pass B: parallel weighted scan of chunk carries ----------------
__global__ __launch_bounds__(256) void scanB_kernel(const float* __restrict__ carry,
                                                    float* __restrict__ carryin,
                                                    const float* __restrict__ log_alpha) {
  __shared__ float S[8][32];
  const int b   = blockIdx.x >> 6;
  const int chg = blockIdx.x & 63;
  const int cg  = threadIdx.x >> 5;   // chunk-group 0..7
  const int chl = threadIdx.x & 31;
  const int ch  = chg * 32 + chl;
  const float alpha = sigmoidf_(log_alpha[ch >> 8]);
  const float lal  = log2f(alpha);
  const float aL   = exp2f((float)CHUNK * lal);        // alpha^32
  const float aL16 = exp2f((float)(CHUNK * 16) * lal); // alpha^512
  const size_t base = ((size_t)b * NCH + cg * 16) * DI + ch;
  float v[16];
  #pragma unroll
  for (int i = 0; i < 16; ++i) v[i] = carry[base + (size_t)i * DI];
  float Sl = v[0];
  #pragma unroll
  for (int i = 1; i < 16; ++i) Sl = fmaf(aL, Sl, v[i]);
  S[cg][chl] = Sl;
  __syncthreads();
  float P = 0.f;
  for (int h = 0; h < cg; ++h) P = fmaf(aL16, P, S[h][chl]);
  #pragma unroll
  for (int i = 0; i < 16; ++i) {
    carryin[base + (size_t)i * DI] = P;
    P = fmaf(aL, P, v[i]);
  }
}

// ---------------- scan pass C: recompute local scan seeded with carry-in, fuse SiLU*gate ----
__global__ __launch_bounds__(256) void scanC_kernel(const bf16_t* __restrict__ xz,
                                                    const float* __restrict__ conv_w,
                                                    const float* __restrict__ conv_b,
                                                    const float* __restrict__ log_alpha,
                                                    const float* __restrict__ carryin,
                                                    bf16_t* __restrict__ act) {
  const int half  = blockIdx.x & 1;
  const int chunk = (blockIdx.x >> 1) & (NCH - 1);
  const int b     = blockIdx.x >> 8;
  const int ch    = half * 1024 + threadIdx.x * 4;
  const float alpha = sigmoidf_(log_alpha[ch >> 8]);
  float w[4][4], bias[4];
  #pragma unroll
  for (int j = 0; j < 4; ++j) {
    const float4 cw = ((const float4*)conv_w)[ch + j];
    w[j][0] = cw.x; w[j][1] = cw.y; w[j][2] = cw.z; w[j][3] = cw.w;
    bias[j] = conv_b[ch + j];
  }
  const int s0 = chunk * CHUNK;
  const size_t base = ((size_t)b * Ss + s0) * XZN + ch;
  float x3[4] = {0,0,0,0}, x2[4] = {0,0,0,0}, x1[4] = {0,0,0,0}, y[4];
  const float4 cin = *(const float4*)(carryin + ((size_t)b * NCH + chunk) * DI + ch);
  y[0] = cin.x; y[1] = cin.y; y[2] = cin.z; y[3] = cin.w;
  if (chunk > 0) {
    const bf16x4 v3 = *(const bf16x4*)(xz + base - 3 * (size_t)XZN);
    const bf16x4 v2 = *(const bf16x4*)(xz + base - 2 * (size_t)XZN);
    const bf16x4 v1 = *(const bf16x4*)(xz + base - 1 * (size_t)XZN);
    #pragma unroll
    for (int j = 0; j < 4; ++j) { x3[j] = (float)v3[j]; x2[j] = (float)v2[j]; x1[j] = (float)v1[j]; }
  }
  const size_t abase = ((size_t)b * Ss + s0) * DI + ch;
  #pragma unroll 4
  for (int t = 0; t < CHUNK; ++t) {
    const bf16x4 v = *(const bf16x4*)(xz + base + (size_t)t * XZN);
    const bf16x4 gv = *(const bf16x4*)(xz + base + (size_t)t * XZN + DI);
    bf16x4 ov;
    #pragma unroll
    for (int j = 0; j < 4; ++j) {
      const float xc = (float)v[j];
      const float cv = bias[j] + w[j][0] * x3[j] + w[j][1] * x2[j] + w[j][2] * x1[j] + w[j][3] * xc;
      x3[j] = x2[j]; x2[j] = x1[j]; x1[j] = xc;
      y[j] = fmaf(alpha, y[j], cv);
      const float o = y[j] * (1.f / (1.f + __expf(-y[j]))) * (float)gv[j];
      ov[j] = (bf16_t)o;
    }
    *(bf16x4*)(act + abase + (size_t)t * DI) = ov;
  }
}

// ---------------- launch ----------------
extern "C" void kernel_launch(void* const* d_in, const int* in_sizes, int n_in,
                              void* d_out, int out_size, void* d_ws, size_t ws_size,
                              hipStream_t stream) {
  const float* x          = (const float*)d_in[0];
  const float* norm_w     = (const float*)d_in[1];
  const float* norm_b     = (const float*)d_in[2];
  const float* in_proj_w  = (const float*)d_in[3];
  const float* conv_w     = (const float*)d_in[4];
  const float* conv_b     = (const float*)d_in[5];
  const float* out_proj_w = (const float*)d_in[6];
  const float* log_alpha  = (const float*)d_in[7];
  float* out = (float*)d_out;

  char* ws = (char*)d_ws;
  bf16_t* xn     = (bf16_t*)(ws);                        // 32 MB (dead after GEMM1)
  bf16_t* w_in   = (bf16_t*)(ws + 33554432);             // 8 MB
  bf16_t* w_out  = (bf16_t*)(ws + 41943040);             // 4 MB
  bf16_t* xz     = (bf16_t*)(ws + 46137344);             // 128 MB
  bf16_t* act    = (bf16_t*)(ws + 180355072);            // 64 MB
  // carry buffers overlay the dead xn region (GEMM1 finished before scanA)
  float*  carry   = (float*)(ws);                        // 4 MB
  float*  carryin = (float*)(ws + 4194304);              // 4 MB

  cvt_kernel<<<4096, 256, 0, stream>>>(in_proj_w, w_in);    // 4096*1024
  cvt_kernel<<<2048, 256, 0, stream>>>(out_proj_w, w_out);  // 1024*2048
  ln_kernel<<<Mtot, 256, 0, stream>>>(x, norm_w, norm_b, xn);

  dim3 g1(XZN / 256, Mtot / 256);   // (16, 64) = 1024 blocks, K-tiles = 32
  gemm256<0><<<g1, 512, 0, stream>>>(xn, w_in, xz, nullptr, Mtot, XZN, Dd);

  scanA_kernel<<<Bb * NCH * 2, 256, 0, stream>>>(xz, conv_w, conv_b, log_alpha, carry);
  scanB_kernel<<<Bb * 64, 256, 0, stream>>>(carry, carryin, log_alpha);
  scanC_kernel<<<Bb * NCH * 2, 256, 0, stream>>>(xz, conv_w, conv_b, log_alpha, carryin, act);

  dim3 g2(Dd / 256, Mtot / 256);    // (4, 64) = 256 blocks = 1 residency round, K-tiles = 64
  gemm256<1><<<g2, 512, 0, stream>>>(act, w_out, out, x, Mtot, Dd, DI);
}

// Round 4
// 392.244 us; speedup vs baseline: 1.0540x; 1.0540x over previous
//
#include <hip/hip_runtime.h>
#include <hip/hip_bf16.h>
#include <cstdint>

// Problem constants
#define Bb 4
#define Ss 4096
#define Dd 1024
#define Hh 8
#define DI 2048
#define HD 256
#define XZN 4096      // 2*DI
#define Mtot 16384    // B*S
#define NCH 128       // scan chunks
#define CHUNK 32      // S / NCH

typedef __bf16 bf16_t;
typedef __bf16 bf16x8 __attribute__((ext_vector_type(8)));
typedef __bf16 bf16x4 __attribute__((ext_vector_type(4)));
typedef float f32x4 __attribute__((ext_vector_type(4)));

__device__ __forceinline__ float sigmoidf_(float x) { return 1.f / (1.f + __expf(-x)); }

// async 16B/lane global->LDS. LDS dest is wave-uniform base + lane*16.
__device__ __forceinline__ void async_ld16(void* lds, const void* g) {
  __builtin_amdgcn_global_load_lds(
      (const __attribute__((address_space(1))) void*)(uintptr_t)g,
      (__attribute__((address_space(3))) void*)(uint32_t)(uintptr_t)lds,
      16, 0, 0);
}

// ---------------- fp32 -> bf16 cast (weights) ----------------
__global__ __launch_bounds__(256) void cvt_kernel(const float* __restrict__ s,
                                                  bf16_t* __restrict__ d) {
  const int i = blockIdx.x * 256 + threadIdx.x;  // one float4 per thread
  const float4 v = ((const float4*)s)[i];
  bf16_t* o = d + 4 * (size_t)i;
  o[0] = (bf16_t)v.x; o[1] = (bf16_t)v.y; o[2] = (bf16_t)v.z; o[3] = (bf16_t)v.w;
}

// ---------------- LayerNorm -> bf16 ----------------
__global__ __launch_bounds__(256) void ln_kernel(const float* __restrict__ x,
                                                 const float* __restrict__ w,
                                                 const float* __restrict__ b,
                                                 bf16_t* __restrict__ xn) {
  __shared__ float red[8];
  const int row = blockIdx.x;
  const float4 v = ((const float4*)(x + (size_t)row * Dd))[threadIdx.x];
  float s  = v.x + v.y + v.z + v.w;
  float s2 = v.x * v.x + v.y * v.y + v.z * v.z + v.w * v.w;
  #pragma unroll
  for (int off = 32; off; off >>= 1) { s += __shfl_down(s, off); s2 += __shfl_down(s2, off); }
  const int wave = threadIdx.x >> 6, lane = threadIdx.x & 63;
  if (lane == 0) { red[wave * 2] = s; red[wave * 2 + 1] = s2; }
  __syncthreads();
  if (threadIdx.x == 0) {
    float S = 0.f, S2 = 0.f;
    for (int i = 0; i < 4; ++i) { S += red[i * 2]; S2 += red[i * 2 + 1]; }
    red[0] = S; red[1] = S2;
  }
  __syncthreads();
  const float mean = red[0] * (1.f / Dd);
  const float var  = red[1] * (1.f / Dd) - mean * mean;
  const float rstd = rsqrtf(var + 1e-5f);
  const float4 wv = ((const float4*)w)[threadIdx.x];
  const float4 bv = ((const float4*)b)[threadIdx.x];
  bf16_t* o = xn + (size_t)row * Dd + threadIdx.x * 4;
  o[0] = (bf16_t)((v.x - mean) * rstd * wv.x + bv.x);
  o[1] = (bf16_t)((v.y - mean) * rstd * wv.y + bv.y);
  o[2] = (bf16_t)((v.z - mean) * rstd * wv.z + bv.z);
  o[3] = (bf16_t)((v.w - mean) * rstd * wv.w + bv.w);
}

// ---------------- GEMM: C[M,N] = A[M,K] @ B[N,K]^T (both K-major bf16) ----------------
// 256x256 tile, BK=64, 8 waves (2M x 4N, each 128x64 out), 16x16x32 bf16 MFMA.
// 8-phase-style fine interleave (T3+T4, m196/m201 mechanism): each BK=64 tile is
// 4 phases; each phase = {4-8 ds_read_b128 for THIS phase's fragments ||
// 2 global_load_lds staging next tile || lgkmcnt(0)+sched_barrier ||
// setprio(1) 16 MFMA setprio(0)}. Waves slip within a 2-phase window so one
// wave's reads overlap another's MFMA burst.
// LDS: 2 buffers x (A 32KB + B 32KB); each matrix split into 2 K-half regions
// (ks0/ks1) of [256 rows][32 cols] with 64B rows.
// Counted-vmcnt bookkeeping (provable): stage order per tile t (for t+1):
// ph0: A-ks0(2 loads), ph1: B-ks0(2), ph2: A-ks1(2), ph3: B-ks1(2).
// At each sync point outstanding == 8; vmcnt(4) drains exactly the K-half group
// about to be read. sync-alpha (loop top) validates ks0; sync-beta (mid-tile)
// validates ks1. Last tile: no stages; beta uses vmcnt(0). Never 0 in steady state.
// WAR safety: stages into buf (t+1)&1 are issued after sync-alpha of tile t;
// all waves' reads of that buffer (tile t-1) were lgkm-drained before their
// ph3 MFMAs, which precede that barrier.
// LDS swizzle (T2): per K-half region, 64B rows of 4x16B chunks,
// phys_chunk = logical ^ ((row>>1)&3); staging pre-swizzles the GLOBAL source
// column group ((l&3)^((l>>3)&3)); measured conflict-free (SQ_LDS_BANK_CONFLICT==0).
template <int ADD_RES>
__global__ __launch_bounds__(512, 2) void gemm256(const bf16_t* __restrict__ A,
                                                  const bf16_t* __restrict__ Bw,
                                                  void* __restrict__ Cv,
                                                  const float* __restrict__ res,
                                                  int M, int N, int K) {
  __shared__ __align__(16) char LDS[131072];  // 2 bufs x (A 32KB | B 32KB)
  const int tid = threadIdx.x;
  const int wave = tid >> 6, lane = tid & 63;
  const int wm = wave >> 2, wn = wave & 3;

  // T1: XCD-aware bijective block swizzle (both grids have nwg % 8 == 0)
  const int nbx = gridDim.x;
  const int nwg = nbx * gridDim.y;
  const int bid0 = blockIdx.y * nbx + blockIdx.x;
  const int cpx = nwg >> 3;
  const int bid = (bid0 & 7) * cpx + (bid0 >> 3);
  const int bm = bid / nbx, bn = bid % nbx;

  f32x4 acc[8][4];
  #pragma unroll
  for (int i = 0; i < 8; ++i)
    #pragma unroll
    for (int j = 0; j < 4; ++j) acc[i][j] = (f32x4){0.f, 0.f, 0.f, 0.f};

  // staging: one async_ld16 per wave covers 1KB = 16 rows x 64B of a K-half
  // region; 8 waves cover 128 rows (one row-half, 8KB). Two calls = 256 rows.
  // lane l -> row w*16 + (l>>2), phys chunk l&3; source col group pre-swizzled:
  // (l&3) ^ ((row>>1)&3) = (l&3) ^ ((l>>3)&3)  (w*8 == 0 mod 4).
  const int scg = (lane & 3) ^ ((lane >> 3) & 3);
  const bf16_t* Ag = A  + (size_t)(bm * 256 + wave * 16 + (lane >> 2)) * K + scg * 8;
  const bf16_t* Bg = Bw + (size_t)(bn * 256 + wave * 16 + (lane >> 2)) * K + scg * 8;
  const size_t rowK128 = (size_t)128 * K;
  char* const LDSw = LDS + wave * 1024;  // + buf*65536 + mat*32768 + ks*16384 (+8192 for row-half 1)

  // fragment LDS byte offsets within a K-half region (constant across tiles)
  const int fr = lane & 15, fq = lane >> 4;
  int aoff[8], boff[4];
  #pragma unroll
  for (int mt = 0; mt < 8; ++mt) {
    const int row = wm * 128 + mt * 16 + fr;
    aoff[mt] = row * 64 + ((fq ^ ((row >> 1) & 3)) << 4);
  }
  #pragma unroll
  for (int nt = 0; nt < 4; ++nt) {
    const int row = wn * 64 + nt * 16 + fr;
    boff[nt] = row * 64 + ((fq ^ ((row >> 1) & 3)) << 4);
  }

  const int NT = K >> 6;   // BK=64 tiles

#define STG(u, mat, ks) do {                                              \
    char* d_ = LDSw + ((u) & 1) * 65536 + (mat) * 32768 + (ks) * 16384;   \
    const bf16_t* s_ = (mat) ? Bg : Ag;                                   \
    const int ko_ = (u) * 64 + (ks) * 32;                                 \
    async_ld16(d_,        s_ + ko_);                                      \
    async_ld16(d_ + 8192, s_ + rowK128 + ko_);                            \
  } while (0)

#define RDA(DST, bufb, ks, g) do {                                        \
    _Pragma("unroll")                                                     \
    for (int i_ = 0; i_ < 4; ++i_)                                        \
      DST[i_] = *(const bf16x8*)(LDS + (bufb) * 65536 + (ks) * 16384 + aoff[(g) * 4 + i_]); \
  } while (0)

#define RDB(DST, bufb, ks) do {                                           \
    _Pragma("unroll")                                                     \
    for (int i_ = 0; i_ < 4; ++i_)                                        \
      DST[i_] = *(const bf16x8*)(LDS + (bufb) * 65536 + 32768 + (ks) * 16384 + boff[i_]); \
  } while (0)

#define MM(AF, BF, g) do {                                                \
    __builtin_amdgcn_s_setprio(1);                                        \
    _Pragma("unroll")                                                     \
    for (int m_ = 0; m_ < 4; ++m_)                                        \
      _Pragma("unroll")                                                   \
      for (int n_ = 0; n_ < 4; ++n_)                                      \
        acc[(g) * 4 + m_][n_] = __builtin_amdgcn_mfma_f32_16x16x32_bf16(  \
            AF[m_], BF[n_], acc[(g) * 4 + m_][n_], 0, 0, 0);              \
    __builtin_amdgcn_s_setprio(0);                                        \
  } while (0)

#define LGKM0 do { asm volatile("s_waitcnt lgkmcnt(0)" ::: "memory");     \
    __builtin_amdgcn_sched_barrier(0); } while (0)
#define VMB4 do { asm volatile("s_waitcnt vmcnt(4)" ::: "memory");        \
    __builtin_amdgcn_s_barrier(); } while (0)
#define VMB0 do { asm volatile("s_waitcnt vmcnt(0)" ::: "memory");        \
    __builtin_amdgcn_s_barrier(); } while (0)

  // prologue: stage tile0 fully, in drain order (A-ks0, B-ks0, A-ks1, B-ks1)
  STG(0, 0, 0); STG(0, 1, 0); STG(0, 0, 1); STG(0, 1, 1);
  bf16x8 af[4], ag[4], bfk[4];

  for (int t = 0; t < NT - 1; ++t) {
    const int cb = t & 1;
    VMB4;                                   // sync alpha: tile t ks0 valid
    RDB(bfk, cb, 0); RDA(af, cb, 0, 0);     // ph0 reads (8)
    STG(t + 1, 0, 0);                       // stage next A-ks0
    LGKM0; MM(af, bfk, 0);                  // 16 MFMA
    RDA(ag, cb, 0, 1);                      // ph1 reads (4)
    STG(t + 1, 1, 0);                       // stage next B-ks0
    LGKM0; MM(ag, bfk, 1);
    VMB4;                                   // sync beta: tile t ks1 valid
    RDB(bfk, cb, 1); RDA(af, cb, 1, 0);     // ph2 reads (8)
    STG(t + 1, 0, 1);                       // stage next A-ks1
    LGKM0; MM(af, bfk, 0);
    RDA(ag, cb, 1, 1);                      // ph3 reads (4)
    STG(t + 1, 1, 1);                       // stage next B-ks1
    LGKM0; MM(ag, bfk, 1);
  }
  {  // last tile: no staging; final drain
    const int cb = (NT - 1) & 1;
    VMB4;
    RDB(bfk, cb, 0); RDA(af, cb, 0, 0);
    LGKM0; MM(af, bfk, 0);
    RDA(ag, cb, 0, 1);
    LGKM0; MM(ag, bfk, 1);
    VMB0;
    RDB(bfk, cb, 1); RDA(af, cb, 1, 0);
    LGKM0; MM(af, bfk, 0);
    RDA(ag, cb, 1, 1);
    LGKM0; MM(ag, bfk, 1);
  }

#undef STG
#undef RDA
#undef RDB
#undef MM
#undef LGKM0
#undef VMB4
#undef VMB0

  // epilogue: D[row=fq*4+r][col=fr] per 16x16 tile
  const int m0 = bm * 256 + wm * 128 + fq * 4;
  const int n0 = bn * 256 + wn * 64 + fr;
  #pragma unroll
  for (int mt = 0; mt < 8; ++mt)
    #pragma unroll
    for (int nt = 0; nt < 4; ++nt)
      #pragma unroll
      for (int r = 0; r < 4; ++r) {
        const size_t m = (size_t)(m0 + mt * 16 + r);
        const size_t n = (size_t)(n0 + nt * 16);
        if (ADD_RES)
          ((float*)Cv)[m * N + n] = acc[mt][nt][r] + res[m * N + n];
        else
          ((bf16_t*)Cv)[m * N + n] = (bf16_t)acc[mt][nt][r];
      }
}

// ---------------- scan pass A: conv + chunk-local scan, carries only ----------------
__global__ __launch_bounds__(256) void scanA_kernel(const bf16_t* __restrict__ xz,
                                                    const float* __restrict__ conv_w,
                                                    const float* __restrict__ conv_b,
                                                    const float* __restrict__ log_alpha,
                                                    float* __restrict__ carry) {
  const int half  = blockIdx.x & 1;
  const int chunk = (blockIdx.x >> 1) & (NCH - 1);
  const int b     = blockIdx.x >> 8;
  const int ch    = half * 1024 + threadIdx.x * 4;
  const float alpha = sigmoidf_(log_alpha[ch >> 8]);
  float w[4][4], bias[4];
  #pragma unroll
  for (int j = 0; j < 4; ++j) {
    const float4 cw = ((const float4*)conv_w)[ch + j];
    w[j][0] = cw.x; w[j][1] = cw.y; w[j][2] = cw.z; w[j][3] = cw.w;
    bias[j] = conv_b[ch + j];
  }
  const int s0 = chunk * CHUNK;
  const size_t base = ((size_t)b * Ss + s0) * XZN + ch;
  float x3[4] = {0,0,0,0}, x2[4] = {0,0,0,0}, x1[4] = {0,0,0,0}, y[4] = {0,0,0,0};
  if (chunk > 0) {
    const bf16x4 v3 = *(const bf16x4*)(xz + base - 3 * (size_t)XZN);
    const bf16x4 v2 = *(const bf16x4*)(xz + base - 2 * (size_t)XZN);
    const bf16x4 v1 = *(const bf16x4*)(xz + base - 1 * (size_t)XZN);
    #pragma unroll
    for (int j = 0; j < 4; ++j) { x3[j] = (float)v3[j]; x2[j] = (float)v2[j]; x1[j] = (float)v1[j]; }
  }
  #pragma unroll 4
  for (int t = 0; t < CHUNK; ++t) {
    const bf16x4 v = *(const bf16x4*)(xz + base + (size_t)t * XZN);
    #pragma unroll
    for (int j = 0; j < 4; ++j) {
      const float xc = (float)v[j];
      const float cv = bias[j] + w[j][0] * x3[j] + w[j][1] * x2[j] + w[j][2] * x1[j] + w[j][3] * xc;
      x3[j] = x2[j]; x2[j] = x1[j]; x1[j] = xc;
      y[j] = fmaf(alpha, y[j], cv);
    }
  }
  *(float4*)(carry + ((size_t)b * NCH + chunk) * DI + ch) =
      make_float4(y[0], y[1], y[2], y[3]);
}

// ---------------- scan pass B: parallel weighted scan of chunk carries ----------------
__global__ __launch_bounds__(256) void scanB_kernel(const float* __restrict__ carry,
                                                    float* __restrict__ carryin,
                                                    const float* __restrict__ log_alpha) {
  __shared__ float S[8][32];
  const int b   = blockIdx.x >> 6;
  const int chg = blockIdx.x & 63;
  const int cg  = threadIdx.x >> 5;   // chunk-group 0..7
  const int chl = threadIdx.x & 31;
  const int ch  = chg * 32 + chl;
  const float alpha = sigmoidf_(log_alpha[ch >> 8]);
  const float lal  = log2f(alpha);
  const float aL   = exp2f((float)CHUNK * lal);        // alpha^32
  const float aL16 = exp2f((float)(CHUNK * 16) * lal); // alpha^512
  const size_t base = ((size_t)b * NCH + cg * 16) * DI + ch;
  float v[16];
  #pragma unroll
  for (int i = 0; i < 16; ++i) v[i] = carry[base + (size_t)i * DI];
  float Sl = v[0];
  #pragma unroll
  for (int i = 1; i < 16; ++i) Sl = fmaf(aL, Sl, v[i]);
  S[cg][chl] = Sl;
  __syncthreads();
  float P = 0.f;
  for (int h = 0; h < cg; ++h) P = fmaf(aL16, P, S[h][chl]);
  #pragma unroll
  for (int i = 0; i < 16; ++i) {
    carryin[base + (size_t)i * DI] = P;
    P = fmaf(aL, P, v[i]);
  }
}

// ---------------- scan pass C: recompute local scan seeded with carry-in, fuse SiLU*gate ----
__global__ __launch_bounds__(256) void scanC_kernel(const bf16_t* __restrict__ xz,
                                                    const float* __restrict__ conv_w,
                                                    const float* __restrict__ conv_b,
                                                    const float* __restrict__ log_alpha,
                                                    const float* __restrict__ carryin,
                                                    bf16_t* __restrict__ act) {
  const int half  = blockIdx.x & 1;
  const int chunk = (blockIdx.x >> 1) & (NCH - 1);
  const int b     = blockIdx.x >> 8;
  const int ch    = half * 1024 + threadIdx.x * 4;
  const float alpha = sigmoidf_(log_alpha[ch >> 8]);
  float w[4][4], bias[4];
  #pragma unroll
  for (int j = 0; j < 4; ++j) {
    const float4 cw = ((const float4*)conv_w)[ch + j];
    w[j][0] = cw.x; w[j][1] = cw.y; w[j][2] = cw.z; w[j][3] = cw.w;
    bias[j] = conv_b[ch + j];
  }
  const int s0 = chunk * CHUNK;
  const size_t base = ((size_t)b * Ss + s0) * XZN + ch;
  float x3[4] = {0,0,0,0}, x2[4] = {0,0,0,0}, x1[4] = {0,0,0,0}, y[4];
  const float4 cin = *(const float4*)(carryin + ((size_t)b * NCH + chunk) * DI + ch);
  y[0] = cin.x; y[1] = cin.y; y[2] = cin.z; y[3] = cin.w;
  if (chunk > 0) {
    const bf16x4 v3 = *(const bf16x4*)(xz + base - 3 * (size_t)XZN);
    const bf16x4 v2 = *(const bf16x4*)(xz + base - 2 * (size_t)XZN);
    const bf16x4 v1 = *(const bf16x4*)(xz + base - 1 * (size_t)XZN);
    #pragma unroll
    for (int j = 0; j < 4; ++j) { x3[j] = (float)v3[j]; x2[j] = (float)v2[j]; x1[j] = (float)v1[j]; }
  }
  const size_t abase = ((size_t)b * Ss + s0) * DI + ch;
  #pragma unroll 4
  for (int t = 0; t < CHUNK; ++t) {
    const bf16x4 v = *(const bf16x4*)(xz + base + (size_t)t * XZN);
    const bf16x4 gv = *(const bf16x4*)(xz + base + (size_t)t * XZN + DI);
    bf16x4 ov;
    #pragma unroll
    for (int j = 0; j < 4; ++j) {
      const float xc = (float)v[j];
      const float cv = bias[j] + w[j][0] * x3[j] + w[j][1] * x2[j] + w[j][2] * x1[j] + w[j][3] * xc;
      x3[j] = x2[j]; x2[j] = x1[j]; x1[j] = xc;
      y[j] = fmaf(alpha, y[j], cv);
      const float o = y[j] * (1.f / (1.f + __expf(-y[j]))) * (float)gv[j];
      ov[j] = (bf16_t)o;
    }
    *(bf16x4*)(act + abase + (size_t)t * DI) = ov;
  }
}

// ---------------- launch ----------------
extern "C" void kernel_launch(void* const* d_in, const int* in_sizes, int n_in,
                              void* d_out, int out_size, void* d_ws, size_t ws_size,
                              hipStream_t stream) {
  const float* x          = (const float*)d_in[0];
  const float* norm_w     = (const float*)d_in[1];
  const float* norm_b     = (const float*)d_in[2];
  const float* in_proj_w  = (const float*)d_in[3];
  const float* conv_w     = (const float*)d_in[4];
  const float* conv_b     = (const float*)d_in[5];
  const float* out_proj_w = (const float*)d_in[6];
  const float* log_alpha  = (const float*)d_in[7];
  float* out = (float*)d_out;

  char* ws = (char*)d_ws;
  bf16_t* xn     = (bf16_t*)(ws);                        // 32 MB (dead after GEMM1)
  bf16_t* w_in   = (bf16_t*)(ws + 33554432);             // 8 MB
  bf16_t* w_out  = (bf16_t*)(ws + 41943040);             // 4 MB
  bf16_t* xz     = (bf16_t*)(ws + 46137344);             // 128 MB
  bf16_t* act    = (bf16_t*)(ws + 180355072);            // 64 MB
  // carry buffers overlay the dead xn region (GEMM1 finished before scanA)
  float*  carry   = (float*)(ws);                        // 4 MB
  float*  carryin = (float*)(ws + 4194304);              // 4 MB

  cvt_kernel<<<4096, 256, 0, stream>>>(in_proj_w, w_in);    // 4096*1024
  cvt_kernel<<<2048, 256, 0, stream>>>(out_proj_w, w_out);  // 1024*2048
  ln_kernel<<<Mtot, 256, 0, stream>>>(x, norm_w, norm_b, xn);

  dim3 g1(XZN / 256, Mtot / 256);   // (16, 64) = 1024 blocks, K-tiles = 16
  gemm256<0><<<g1, 512, 0, stream>>>(xn, w_in, xz, nullptr, Mtot, XZN, Dd);

  scanA_kernel<<<Bb * NCH * 2, 256, 0, stream>>>(xz, conv_w, conv_b, log_alpha, carry);
  scanB_kernel<<<Bb * 64, 256, 0, stream>>>(carry, carryin, log_alpha);
  scanC_kernel<<<Bb * NCH * 2, 256, 0, stream>>>(xz, conv_w, conv_b, log_alpha, carryin, act);

  dim3 g2(Dd / 256, Mtot / 256);    // (4, 64) = 256 blocks = 1 residency round, K-tiles = 32
  gemm256<1><<<g2, 512, 0, stream>>>(act, w_out, out, x, Mtot, Dd, DI);
}